// Round 2
// baseline (566.824 us; speedup 1.0000x reference)
//
#include <hip/hip_runtime.h>
#include <hip/hip_bf16.h>

#define SEQ 2048
#define NB 8
#define DIM 1024

typedef __attribute__((ext_vector_type(4))) float f32x4;
typedef __attribute__((ext_vector_type(8))) short bf16x8;
typedef __attribute__((ext_vector_type(4))) unsigned short u16x4;

__device__ __forceinline__ unsigned short f2bf(float f) {
    union { float f; unsigned u; } x; x.f = f;
    unsigned r = x.u + 0x7fffu + ((x.u >> 16) & 1u);
    return (unsigned short)(r >> 16);
}
__device__ __forceinline__ float bf2f(unsigned short u) {
    union { unsigned u; float f; } x; x.u = ((unsigned)u) << 16;
    return x.f;
}

// ---------------- weight convert: fp32 -> bf16, 1M elements ----------------
__global__ __launch_bounds__(256) void convert_w(const float* __restrict__ in,
                                                 unsigned short* __restrict__ out) {
    int i = blockIdx.x * 256 + threadIdx.x;      // vec4 index; grid covers D*D/4
    float4 v = reinterpret_cast<const float4*>(in)[i];
    u16x4 o = { f2bf(v.x), f2bf(v.y), f2bf(v.z), f2bf(v.w) };
    reinterpret_cast<u16x4*>(out)[i] = o;
}

// ---------------- xb[b][s][d] = bf16(seq[s][b][d]) ----------------
__global__ __launch_bounds__(256) void make_xb(const float* __restrict__ seq,
                                               unsigned short* __restrict__ xb) {
    int sb = blockIdx.x;           // = s*NB + b (seq row order)
    int s = sb >> 3, b = sb & 7;
    const float4* src = reinterpret_cast<const float4*>(seq + (size_t)sb * DIM);
    u16x4* dst = reinterpret_cast<u16x4*>(xb + ((size_t)b * SEQ + s) * DIM);
    int t = threadIdx.x;
    float4 v = src[t];
    u16x4 o = { f2bf(v.x), f2bf(v.y), f2bf(v.z), f2bf(v.w) };
    dst[t] = o;
}

// ---------------- xbT[b][d][s] = bf16(seq[s][b][d]) (64x64 LDS transpose) ----
__global__ __launch_bounds__(256) void make_xbT(const float* __restrict__ seq,
                                                unsigned short* __restrict__ xbT) {
    __shared__ unsigned short tile[64][65];
    int s0 = blockIdx.x * 64, d0 = blockIdx.y * 64, b = blockIdx.z;
    int t = threadIdx.x;
    int dx = (t & 15) * 4, sy = t >> 4;
    #pragma unroll
    for (int i = 0; i < 4; ++i) {
        int s = s0 + sy + i * 16;
        float4 v = *reinterpret_cast<const float4*>(seq + ((size_t)s * NB + b) * DIM + d0 + dx);
        tile[sy + i * 16][dx + 0] = f2bf(v.x);
        tile[sy + i * 16][dx + 1] = f2bf(v.y);
        tile[sy + i * 16][dx + 2] = f2bf(v.z);
        tile[sy + i * 16][dx + 3] = f2bf(v.w);
    }
    __syncthreads();
    int sx = (t & 15) * 4, dy = t >> 4;
    #pragma unroll
    for (int i = 0; i < 4; ++i) {
        int d = d0 + dy + i * 16;
        u16x4 o = { tile[sx + 0][dy + i * 16], tile[sx + 1][dy + i * 16],
                    tile[sx + 2][dy + i * 16], tile[sx + 3][dy + i * 16] };
        *reinterpret_cast<u16x4*>(xbT + ((size_t)b * DIM + d) * SEQ + s0 + sx) = o;
    }
}

// ---------------- GEMM: C = op(A[M,K] @ B[N,K]^T) ----------------
// m97 structure: 128x128 tile, BK=32, 4 waves (2x2 of 64x64), global_load_lds w16.
// MODE 0: C bf16 = tanh(acc), no batch offset
// MODE 1: C f32  = acc*scale, C += sC*bz
// MODE 2: C bf16 = acc*scale, C += sC*bz
__device__ __forceinline__ void gload16(const unsigned short* g, unsigned short* l) {
    __builtin_amdgcn_global_load_lds((const __attribute__((address_space(1))) void*)g,
                                     (__attribute__((address_space(3))) void*)l,
                                     16, 0, 0);
}

template<int MODE>
__global__ __launch_bounds__(256) void gemm_bt(
    const unsigned short* __restrict__ A, size_t sA,
    const unsigned short* __restrict__ B, size_t sB,
    void* __restrict__ Cv, size_t sC,
    int ldc, int K, float scale)
{
    __shared__ unsigned short As[128 * 32];
    __shared__ unsigned short Bs[128 * 32];

    const int bz = blockIdx.z;
    const unsigned short* Ab = A + sA * bz;
    const unsigned short* Bb = B + sB * bz;
    const int m0 = blockIdx.y * 128;
    const int n0 = blockIdx.x * 128;
    const int t = threadIdx.x;
    const int lane = t & 63;
    const int w = t >> 6;
    const int wm = (w >> 1) * 64;
    const int wn = (w & 1) * 64;

    // staging: thread t loads 16B; tile row-major [128][32] bf16
    const int srow = t >> 2;
    const int scol = (t & 3) * 8;
    const unsigned short* ga0 = Ab + (size_t)(m0 + srow) * K + scol;
    const unsigned short* ga1 = Ab + (size_t)(m0 + 64 + srow) * K + scol;
    const unsigned short* gb0 = Bb + (size_t)(n0 + srow) * K + scol;
    const unsigned short* gb1 = Bb + (size_t)(n0 + 64 + srow) * K + scol;
    unsigned short* lA0 = &As[w * 512];
    unsigned short* lA1 = &As[2048 + w * 512];
    unsigned short* lB0 = &Bs[w * 512];
    unsigned short* lB1 = &Bs[2048 + w * 512];

    f32x4 acc[4][4] = {};

    const int fr = lane & 15;
    const int fk = (lane >> 4) * 8;

    for (int k0 = 0; k0 < K; k0 += 32) {
        gload16(ga0 + k0, lA0);
        gload16(ga1 + k0, lA1);
        gload16(gb0 + k0, lB0);
        gload16(gb1 + k0, lB1);
        asm volatile("s_waitcnt vmcnt(0)" ::: "memory");
        __syncthreads();

        bf16x8 af[4], bfv[4];
        #pragma unroll
        for (int mi = 0; mi < 4; ++mi)
            af[mi] = *reinterpret_cast<const bf16x8*>(&As[(wm + mi * 16 + fr) * 32 + fk]);
        #pragma unroll
        for (int ni = 0; ni < 4; ++ni)
            bfv[ni] = *reinterpret_cast<const bf16x8*>(&Bs[(wn + ni * 16 + fr) * 32 + fk]);
        #pragma unroll
        for (int mi = 0; mi < 4; ++mi)
            #pragma unroll
            for (int ni = 0; ni < 4; ++ni)
                acc[mi][ni] = __builtin_amdgcn_mfma_f32_16x16x32_bf16(af[mi], bfv[ni], acc[mi][ni], 0, 0, 0);
        __syncthreads();
    }

    const int orow = (lane >> 4) * 4;   // C/D layout: col=lane&15, row=(lane>>4)*4+r
    const int ocol = lane & 15;
    #pragma unroll
    for (int mi = 0; mi < 4; ++mi)
        #pragma unroll
        for (int ni = 0; ni < 4; ++ni)
            #pragma unroll
            for (int r = 0; r < 4; ++r) {
                int row = m0 + wm + mi * 16 + orow + r;
                int col = n0 + wn + ni * 16 + ocol;
                if (MODE == 0) {
                    unsigned short* C = reinterpret_cast<unsigned short*>(Cv);
                    C[(size_t)row * ldc + col] = f2bf(tanhf(acc[mi][ni][r]));
                } else if (MODE == 1) {
                    float* C = reinterpret_cast<float*>(Cv) + sC * bz;
                    C[(size_t)row * ldc + col] = acc[mi][ni][r] * scale;
                } else {
                    unsigned short* C = reinterpret_cast<unsigned short*>(Cv) + sC * bz;
                    C[(size_t)row * ldc + col] = f2bf(acc[mi][ni][r] * scale);
                }
            }
}

// ------------- in-place row softmax on bf16 logits, row length SEQ ----------
__global__ __launch_bounds__(256) void softmax_rows_bf16(unsigned short* __restrict__ Z) {
    const size_t row = blockIdx.x;
    unsigned short* z = Z + row * SEQ;
    const int t = threadIdx.x;
    u16x4 v0 = reinterpret_cast<const u16x4*>(z)[2 * t];
    u16x4 v1 = reinterpret_cast<const u16x4*>(z)[2 * t + 1];
    float f[8] = { bf2f(v0[0]), bf2f(v0[1]), bf2f(v0[2]), bf2f(v0[3]),
                   bf2f(v1[0]), bf2f(v1[1]), bf2f(v1[2]), bf2f(v1[3]) };
    float m = f[0];
    #pragma unroll
    for (int j = 1; j < 8; ++j) m = fmaxf(m, f[j]);
    #pragma unroll
    for (int off = 32; off; off >>= 1) m = fmaxf(m, __shfl_xor(m, off, 64));
    __shared__ float redm[4], reds[4];
    const int w = t >> 6, lane = t & 63;
    if (lane == 0) redm[w] = m;
    __syncthreads();
    m = fmaxf(fmaxf(redm[0], redm[1]), fmaxf(redm[2], redm[3]));
    float e[8], s = 0.f;
    #pragma unroll
    for (int j = 0; j < 8; ++j) { e[j] = __expf(f[j] - m); s += e[j]; }
    #pragma unroll
    for (int off = 32; off; off >>= 1) s += __shfl_xor(s, off, 64);
    if (lane == 0) reds[w] = s;
    __syncthreads();
    s = reds[0] + reds[1] + reds[2] + reds[3];
    float inv = 1.0f / s;
    u16x4 o0 = { f2bf(e[0] * inv), f2bf(e[1] * inv), f2bf(e[2] * inv), f2bf(e[3] * inv) };
    u16x4 o1 = { f2bf(e[4] * inv), f2bf(e[5] * inv), f2bf(e[6] * inv), f2bf(e[7] * inv) };
    reinterpret_cast<u16x4*>(z)[2 * t] = o0;
    reinterpret_cast<u16x4*>(z)[2 * t + 1] = o1;
}

// ---------------- launch ----------------
extern "C" void kernel_launch(void* const* d_in, const int* in_sizes, int n_in,
                              void* d_out, int out_size, void* d_ws, size_t ws_size,
                              hipStream_t stream) {
    const float* seq  = (const float*)d_in[0];
    const float* Kw1f = (const float*)d_in[1];
    const float* Kw2f = (const float*)d_in[2];
    const float* Qw1f = (const float*)d_in[3];
    const float* Qw2f = (const float*)d_in[4];
    float* out = (float*)d_out;

    // Workspace layout (168 MiB total):
    //   W 8 MiB | xb/qrs 32 MiB | h/xbT 32 MiB | keys 32 MiB | logits(P) 64 MiB
    char* ws = (char*)d_ws;
    size_t off = 0;
    auto alloc = [&](size_t bytes) { void* p = ws + off; off += bytes; return p; };
    const size_t WBYTES = (size_t)DIM * DIM * 2;          // 2 MiB
    const size_t XBYTES = (size_t)NB * SEQ * DIM * 2;     // 32 MiB
    unsigned short* Wk1 = (unsigned short*)alloc(WBYTES);
    unsigned short* Wk2 = (unsigned short*)alloc(WBYTES);
    unsigned short* Wq1 = (unsigned short*)alloc(WBYTES);
    unsigned short* Wq2 = (unsigned short*)alloc(WBYTES);
    unsigned short* xb   = (unsigned short*)alloc(XBYTES);   // later reused as qrs
    unsigned short* hbuf = (unsigned short*)alloc(XBYTES);   // later reused as xbT
    unsigned short* keys = (unsigned short*)alloc(XBYTES);
    unsigned short* P    = (unsigned short*)alloc((size_t)NB * SEQ * SEQ * 2);  // 64 MiB
    unsigned short* qrs = xb;    // xb dead after last MLP input use
    unsigned short* xbT = hbuf;  // hbuf dead after MLP chains

    // weights -> bf16
    convert_w<<<DIM * DIM / 4 / 256, 256, 0, stream>>>(Kw1f, Wk1);
    convert_w<<<DIM * DIM / 4 / 256, 256, 0, stream>>>(Kw2f, Wk2);
    convert_w<<<DIM * DIM / 4 / 256, 256, 0, stream>>>(Qw1f, Wq1);
    convert_w<<<DIM * DIM / 4 / 256, 256, 0, stream>>>(Qw2f, Wq2);
    // x -> [B,S,D] bf16
    make_xb<<<SEQ * NB, 256, 0, stream>>>(seq, xb);

    // MLPs: [NB*SEQ, DIM] x [DIM, DIM]^T, tanh epilogue
    dim3 gMLP(DIM / 128, (NB * SEQ) / 128, 1);
    gemm_bt<0><<<gMLP, 256, 0, stream>>>(xb,   0, Wk1, 0, hbuf, 0, DIM, DIM, 1.0f);
    gemm_bt<0><<<gMLP, 256, 0, stream>>>(hbuf, 0, Wk2, 0, keys, 0, DIM, DIM, 1.0f);
    gemm_bt<0><<<gMLP, 256, 0, stream>>>(xb,   0, Wq1, 0, hbuf, 0, DIM, DIM, 1.0f);
    gemm_bt<0><<<gMLP, 256, 0, stream>>>(hbuf, 0, Wq2, 0, qrs,  0, DIM, DIM, 1.0f);  // writes xb

    // logits[b,s,t] = keys[b,s,:] . qrs[b,t,:] * 1/sqrt(D)  (bf16 out)
    dim3 gQK(SEQ / 128, SEQ / 128, NB);
    gemm_bt<2><<<gQK, 256, 0, stream>>>(keys, (size_t)SEQ * DIM, qrs, (size_t)SEQ * DIM,
                                        P, (size_t)SEQ * SEQ, SEQ, DIM, 0.03125f);

    // softmax in-place (bf16 -> bf16)
    softmax_rows_bf16<<<NB * SEQ, 256, 0, stream>>>(P);

    // V^T for PV (built only now; aliases hbuf)
    make_xbT<<<dim3(SEQ / 64, DIM / 64, NB), 256, 0, stream>>>(seq, xbT);

    // attended[b,s,:] = P[b,s,:] @ xb[b]; write straight into out[s, b, :]
    dim3 gPV(DIM / 128, SEQ / 128, NB);
    gemm_bt<1><<<gPV, 256, 0, stream>>>(P, (size_t)SEQ * SEQ, xbT, (size_t)DIM * SEQ,
                                        out, (size_t)DIM, NB * DIM, SEQ, 1.0f);
}

// Round 4
// 397.585 us; speedup vs baseline: 1.4257x; 1.4257x over previous
//
#include <hip/hip_runtime.h>
#include <hip/hip_bf16.h>

#define SEQ 2048
#define NB 8
#define DIM 1024

typedef __attribute__((ext_vector_type(4))) float f32x4;
typedef __attribute__((ext_vector_type(8))) short bf16x8;
typedef __attribute__((ext_vector_type(4))) unsigned short u16x4;

__device__ __forceinline__ unsigned short f2bf(float f) {
    union { float f; unsigned u; } x; x.f = f;
    unsigned r = x.u + 0x7fffu + ((x.u >> 16) & 1u);
    return (unsigned short)(r >> 16);
}
__device__ __forceinline__ float bf2f(unsigned short u) {
    union { unsigned u; float f; } x; x.u = ((unsigned)u) << 16;
    return x.f;
}

// ---------------- weight convert: fp32 -> bf16 ----------------
__global__ __launch_bounds__(256) void convert_w(const float* __restrict__ in,
                                                 unsigned short* __restrict__ out) {
    int i = blockIdx.x * 256 + threadIdx.x;
    float4 v = reinterpret_cast<const float4*>(in)[i];
    u16x4 o = { f2bf(v.x), f2bf(v.y), f2bf(v.z), f2bf(v.w) };
    reinterpret_cast<u16x4*>(out)[i] = o;
}

// ---------------- xb[b][s][d] = bf16(seq[s][b][d]) ----------------
__global__ __launch_bounds__(256) void make_xb(const float* __restrict__ seq,
                                               unsigned short* __restrict__ xb) {
    int sb = blockIdx.x;
    int s = sb >> 3, b = sb & 7;
    const float4* src = reinterpret_cast<const float4*>(seq + (size_t)sb * DIM);
    u16x4* dst = reinterpret_cast<u16x4*>(xb + ((size_t)b * SEQ + s) * DIM);
    int t = threadIdx.x;
    float4 v = src[t];
    u16x4 o = { f2bf(v.x), f2bf(v.y), f2bf(v.z), f2bf(v.w) };
    dst[t] = o;
}

// ---------------- xbT[b][d][s] = bf16(seq[s][b][d]) ----------------
__global__ __launch_bounds__(256) void make_xbT(const float* __restrict__ seq,
                                                unsigned short* __restrict__ xbT) {
    __shared__ unsigned short tile[64][65];
    int s0 = blockIdx.x * 64, d0 = blockIdx.y * 64, b = blockIdx.z;
    int t = threadIdx.x;
    int dx = (t & 15) * 4, sy = t >> 4;
    #pragma unroll
    for (int i = 0; i < 4; ++i) {
        int s = s0 + sy + i * 16;
        float4 v = *reinterpret_cast<const float4*>(seq + ((size_t)s * NB + b) * DIM + d0 + dx);
        tile[sy + i * 16][dx + 0] = f2bf(v.x);
        tile[sy + i * 16][dx + 1] = f2bf(v.y);
        tile[sy + i * 16][dx + 2] = f2bf(v.z);
        tile[sy + i * 16][dx + 3] = f2bf(v.w);
    }
    __syncthreads();
    int sx = (t & 15) * 4, dy = t >> 4;
    #pragma unroll
    for (int i = 0; i < 4; ++i) {
        int d = d0 + dy + i * 16;
        u16x4 o = { tile[sx + 0][dy + i * 16], tile[sx + 1][dy + i * 16],
                    tile[sx + 2][dy + i * 16], tile[sx + 3][dy + i * 16] };
        *reinterpret_cast<u16x4*>(xbT + ((size_t)b * DIM + d) * SEQ + s0 + sx) = o;
    }
}

// =====================  256x256 8-phase GEMM  =====================
// C[M,N] = op(A[M,K] @ B[N,K]^T). BM=BN=256, BK=64, 8 waves (2M x 4N), 512 thr.
// LDS 128 KiB: As/Bs[2 buf][2 half][128x64]. T2 granule-XOR swizzle via
// pre-swizzled global source (linear LDS dest) + swizzled ds_read.
// Read schedule (per wave): P1: b0-3 + a0,a1 | P2: a2,a3 | P3: a4-7 | P4: none.
// Stage schedule (all distance-2, into slot just freed):
//   P2: B0,B1(t+2)  [B reads done after P1]   P4: A0,A1(t+2) [A reads done after P3]
// vmcnt(8) at P4 leaves exactly tile t+1's 8 loads outstanding -> confirms t+1.
__device__ __forceinline__ void gload16(const unsigned short* g, unsigned short* l) {
    __builtin_amdgcn_global_load_lds((const __attribute__((address_space(1))) void*)g,
                                     (__attribute__((address_space(3))) void*)l,
                                     16, 0, 0);
}

#define QUAD(A0, A1)                                                                              \
    _Pragma("unroll")                                                                             \
    for (int ni = 0; ni < 4; ++ni) {                                                              \
        acc[A0][ni] = __builtin_amdgcn_mfma_f32_16x16x32_bf16(a[A0][0], b[ni][0], acc[A0][ni], 0, 0, 0); \
        acc[A0][ni] = __builtin_amdgcn_mfma_f32_16x16x32_bf16(a[A0][1], b[ni][1], acc[A0][ni], 0, 0, 0); \
        acc[A1][ni] = __builtin_amdgcn_mfma_f32_16x16x32_bf16(a[A1][0], b[ni][0], acc[A1][ni], 0, 0, 0); \
        acc[A1][ni] = __builtin_amdgcn_mfma_f32_16x16x32_bf16(a[A1][1], b[ni][1], acc[A1][ni], 0, 0, 0); \
    }

// MODE 0: C bf16 = tanh(acc); MODE 1: C f32 = acc*scale (+sC*bz); MODE 2: C bf16 = acc*scale (+sC*bz)
template<int MODE>
__global__ __launch_bounds__(512, 2) void gemm256(
    const unsigned short* __restrict__ A, size_t sA,
    const unsigned short* __restrict__ B, size_t sB,
    void* __restrict__ Cv, size_t sC,
    int ldc, int K, float scale)
{
    __shared__ unsigned short As[2][2][8192];   // [buf][half][128*64]
    __shared__ unsigned short Bs[2][2][8192];

    // ---- T1: bijective XCD swizzle (all grids divisible by 8) ----
    const int gx = gridDim.x, gy = gridDim.y;
    const int nwg = gx * gy * gridDim.z;
    const int fid = blockIdx.x + gx * (blockIdx.y + gy * blockIdx.z);
    const int cpx = nwg >> 3;
    const int sw = (fid & 7) * cpx + (fid >> 3);
    const int bx = sw % gx;
    const int rem = sw / gx;
    const int by = rem % gy;
    const int bz = rem / gy;

    const unsigned short* Ab = A + sA * bz;
    const unsigned short* Bb = B + sB * bz;
    const int m0 = by * 256;
    const int n0 = bx * 256;

    const int t_ = threadIdx.x;
    const int lane = t_ & 63;
    const int w = t_ >> 6;          // wave 0..7
    const int wm = w >> 2;          // 0..1 -> A half
    const int wn = w & 3;           // 0..3 -> 64-col block

    // stage-side lane decomposition (8 rows x 8 granules)
    const int l3 = lane >> 3;
    const int g7 = lane & 7;
    // pre-swizzled source: LDS[row][g] holds global[row][g ^ (row&7)]
    const unsigned short* baseA = Ab + (size_t)(m0 + w * 16 + l3) * K + ((g7 ^ l3) << 3);
    const unsigned short* baseB = Bb + (size_t)(n0 + w * 16 + l3) * K + ((g7 ^ l3) << 3);

    auto stgA = [&](int half, int kt) {
        const unsigned short* g = baseA + (size_t)half * 128 * K + (size_t)kt * 64;
        unsigned short* l = &As[kt & 1][half][w * 1024];
        gload16(g, l);
        gload16(g + 8 * (size_t)K, l + 512);
    };
    auto stgB = [&](int half, int kt) {
        const unsigned short* g = baseB + (size_t)half * 128 * K + (size_t)kt * 64;
        unsigned short* l = &Bs[kt & 1][half][w * 1024];
        gload16(g, l);
        gload16(g + 8 * (size_t)K, l + 512);
    };

    // read-side fragment addressing
    const int fr = lane & 15;
    const int hi4 = lane >> 4;
    const int fr64 = fr * 64;
    const int slot0 = ((hi4) ^ g7) << 3;       // k-granule hi4,   deswizzled
    const int slot1 = ((4 + hi4) ^ g7) << 3;   // k-granule 4+hi4, deswizzled
    const int bno = (wn & 1) * 4096;

    f32x4 acc[8][4] = {};
    const int NT = K >> 6;

    // ---- prologue: stage tiles 0 (buf0) and 1 (buf1); confirm tile0 ----
    stgA(0, 0); stgA(1, 0); stgB(0, 0); stgB(1, 0);
    stgA(0, 1); stgA(1, 1); stgB(0, 1); stgB(1, 1);
    asm volatile("s_waitcnt vmcnt(8)" ::: "memory");
    __builtin_amdgcn_s_barrier();

    for (int t = 0; t < NT; ++t) {
        unsigned short* pA = As[t & 1][wm];
        unsigned short* pB = Bs[t & 1][wn >> 1];
        bf16x8 a[8][2], b[4][2];

        // ---------- P1: read b0-3 + a0,a1 ; MFMA a01 ----------
        #pragma unroll
        for (int j = 0; j < 4; ++j) {
            b[j][0] = *(const bf16x8*)&pB[bno + j * 1024 + fr64 + slot0];
            b[j][1] = *(const bf16x8*)&pB[bno + j * 1024 + fr64 + slot1];
        }
        #pragma unroll
        for (int i = 0; i < 2; ++i) {
            a[i][0] = *(const bf16x8*)&pA[i * 1024 + fr64 + slot0];
            a[i][1] = *(const bf16x8*)&pA[i * 1024 + fr64 + slot1];
        }
        __builtin_amdgcn_s_barrier();
        asm volatile("s_waitcnt lgkmcnt(0)" ::: "memory");
        __builtin_amdgcn_sched_barrier(0);
        __builtin_amdgcn_s_setprio(1);
        QUAD(0, 1)
        __builtin_amdgcn_s_setprio(0);
        __builtin_amdgcn_s_barrier();

        // ---------- P2: read a2,a3 ; stage B0,B1(t+2) ; MFMA a23 ----------
        #pragma unroll
        for (int i = 2; i < 4; ++i) {
            a[i][0] = *(const bf16x8*)&pA[i * 1024 + fr64 + slot0];
            a[i][1] = *(const bf16x8*)&pA[i * 1024 + fr64 + slot1];
        }
        if (t + 2 < NT) { stgB(0, t + 2); stgB(1, t + 2); }
        __builtin_amdgcn_s_barrier();
        asm volatile("s_waitcnt lgkmcnt(0)" ::: "memory");
        __builtin_amdgcn_sched_barrier(0);
        __builtin_amdgcn_s_setprio(1);
        QUAD(2, 3)
        __builtin_amdgcn_s_setprio(0);
        __builtin_amdgcn_s_barrier();

        // ---------- P3: read a4-7 ; MFMA a45 ----------
        #pragma unroll
        for (int i = 4; i < 8; ++i) {
            a[i][0] = *(const bf16x8*)&pA[i * 1024 + fr64 + slot0];
            a[i][1] = *(const bf16x8*)&pA[i * 1024 + fr64 + slot1];
        }
        __builtin_amdgcn_s_barrier();
        asm volatile("s_waitcnt lgkmcnt(0)" ::: "memory");
        __builtin_amdgcn_sched_barrier(0);
        __builtin_amdgcn_s_setprio(1);
        QUAD(4, 5)
        __builtin_amdgcn_s_setprio(0);
        __builtin_amdgcn_s_barrier();

        // ---------- P4: stage A0,A1(t+2) ; vmcnt ; MFMA a67 ----------
        if (t + 2 < NT) {
            stgA(0, t + 2); stgA(1, t + 2);
            asm volatile("s_waitcnt vmcnt(8)" ::: "memory");  // leaves tile t+2 in flight; confirms t+1
        } else {
            asm volatile("s_waitcnt vmcnt(0)" ::: "memory");
        }
        __builtin_amdgcn_s_barrier();
        __builtin_amdgcn_sched_barrier(0);
        __builtin_amdgcn_s_setprio(1);
        QUAD(6, 7)
        __builtin_amdgcn_s_setprio(0);
        __builtin_amdgcn_s_barrier();
    }

    // ---- epilogue: C/D layout col=lane&15, row=(lane>>4)*4+r ----
    #pragma unroll
    for (int mi = 0; mi < 8; ++mi)
        #pragma unroll
        for (int ni = 0; ni < 4; ++ni)
            #pragma unroll
            for (int r = 0; r < 4; ++r) {
                int row = m0 + wm * 128 + mi * 16 + hi4 * 4 + r;
                int col = n0 + wn * 64 + ni * 16 + fr;
                if (MODE == 0) {
                    unsigned short* C = reinterpret_cast<unsigned short*>(Cv);
                    C[(size_t)row * ldc + col] = f2bf(tanhf(acc[mi][ni][r]));
                } else if (MODE == 1) {
                    float* C = reinterpret_cast<float*>(Cv) + sC * bz;
                    C[(size_t)row * ldc + col] = acc[mi][ni][r] * scale;
                } else {
                    unsigned short* C = reinterpret_cast<unsigned short*>(Cv) + sC * bz;
                    C[(size_t)row * ldc + col] = f2bf(acc[mi][ni][r] * scale);
                }
            }
}

// ------------- in-place row softmax on bf16 logits ----------
__global__ __launch_bounds__(256) void softmax_rows_bf16(unsigned short* __restrict__ Z) {
    const size_t row = blockIdx.x;
    unsigned short* z = Z + row * SEQ;
    const int t = threadIdx.x;
    u16x4 v0 = reinterpret_cast<const u16x4*>(z)[2 * t];
    u16x4 v1 = reinterpret_cast<const u16x4*>(z)[2 * t + 1];
    float f[8] = { bf2f(v0[0]), bf2f(v0[1]), bf2f(v0[2]), bf2f(v0[3]),
                   bf2f(v1[0]), bf2f(v1[1]), bf2f(v1[2]), bf2f(v1[3]) };
    float m = f[0];
    #pragma unroll
    for (int j = 1; j < 8; ++j) m = fmaxf(m, f[j]);
    #pragma unroll
    for (int off = 32; off; off >>= 1) m = fmaxf(m, __shfl_xor(m, off, 64));
    __shared__ float redm[4], reds[4];
    const int w = t >> 6, lane = t & 63;
    if (lane == 0) redm[w] = m;
    __syncthreads();
    m = fmaxf(fmaxf(redm[0], redm[1]), fmaxf(redm[2], redm[3]));
    float e[8], s = 0.f;
    #pragma unroll
    for (int j = 0; j < 8; ++j) { e[j] = __expf(f[j] - m); s += e[j]; }
    #pragma unroll
    for (int off = 32; off; off >>= 1) s += __shfl_xor(s, off, 64);
    if (lane == 0) reds[w] = s;
    __syncthreads();
    s = reds[0] + reds[1] + reds[2] + reds[3];
    float inv = 1.0f / s;
    u16x4 o0 = { f2bf(e[0] * inv), f2bf(e[1] * inv), f2bf(e[2] * inv), f2bf(e[3] * inv) };
    u16x4 o1 = { f2bf(e[4] * inv), f2bf(e[5] * inv), f2bf(e[6] * inv), f2bf(e[7] * inv) };
    reinterpret_cast<u16x4*>(z)[2 * t] = o0;
    reinterpret_cast<u16x4*>(z)[2 * t + 1] = o1;
}

// ---------------- launch ----------------
extern "C" void kernel_launch(void* const* d_in, const int* in_sizes, int n_in,
                              void* d_out, int out_size, void* d_ws, size_t ws_size,
                              hipStream_t stream) {
    const float* seq  = (const float*)d_in[0];
    const float* Kw1f = (const float*)d_in[1];
    const float* Kw2f = (const float*)d_in[2];
    const float* Qw1f = (const float*)d_in[3];
    const float* Qw2f = (const float*)d_in[4];
    float* out = (float*)d_out;

    // Workspace (168 MiB): W 8 | xb/qrs 32 | h/xbT 32 | keys 32 | logits(P) 64
    char* ws = (char*)d_ws;
    size_t off = 0;
    auto alloc = [&](size_t bytes) { void* p = ws + off; off += bytes; return p; };
    const size_t WBYTES = (size_t)DIM * DIM * 2;
    const size_t XBYTES = (size_t)NB * SEQ * DIM * 2;
    unsigned short* Wk1 = (unsigned short*)alloc(WBYTES);
    unsigned short* Wk2 = (unsigned short*)alloc(WBYTES);
    unsigned short* Wq1 = (unsigned short*)alloc(WBYTES);
    unsigned short* Wq2 = (unsigned short*)alloc(WBYTES);
    unsigned short* xb   = (unsigned short*)alloc(XBYTES);   // reused as qrs
    unsigned short* hbuf = (unsigned short*)alloc(XBYTES);   // reused as xbT
    unsigned short* keys = (unsigned short*)alloc(XBYTES);
    unsigned short* P    = (unsigned short*)alloc((size_t)NB * SEQ * SEQ * 2);
    unsigned short* qrs = xb;
    unsigned short* xbT = hbuf;

    convert_w<<<DIM * DIM / 4 / 256, 256, 0, stream>>>(Kw1f, Wk1);
    convert_w<<<DIM * DIM / 4 / 256, 256, 0, stream>>>(Kw2f, Wk2);
    convert_w<<<DIM * DIM / 4 / 256, 256, 0, stream>>>(Qw1f, Wq1);
    convert_w<<<DIM * DIM / 4 / 256, 256, 0, stream>>>(Qw2f, Wq2);
    make_xb<<<SEQ * NB, 256, 0, stream>>>(seq, xb);

    // MLPs: [16384,1024] x [1024,1024]^T, tanh epilogue
    dim3 gMLP(DIM / 256, (NB * SEQ) / 256, 1);
    gemm256<0><<<gMLP, 512, 0, stream>>>(xb,   0, Wk1, 0, hbuf, 0, DIM, DIM, 1.0f);
    gemm256<0><<<gMLP, 512, 0, stream>>>(hbuf, 0, Wk2, 0, keys, 0, DIM, DIM, 1.0f);
    gemm256<0><<<gMLP, 512, 0, stream>>>(xb,   0, Wq1, 0, hbuf, 0, DIM, DIM, 1.0f);
    gemm256<0><<<gMLP, 512, 0, stream>>>(hbuf, 0, Wq2, 0, qrs,  0, DIM, DIM, 1.0f);

    // logits[b,s,t] = keys[b,s,:].qrs[b,t,:] / sqrt(D)  (bf16 out)
    dim3 gQK(SEQ / 256, SEQ / 256, NB);
    gemm256<2><<<gQK, 512, 0, stream>>>(keys, (size_t)SEQ * DIM, qrs, (size_t)SEQ * DIM,
                                        P, (size_t)SEQ * SEQ, SEQ, DIM, 0.03125f);

    softmax_rows_bf16<<<NB * SEQ, 256, 0, stream>>>(P);

    make_xbT<<<dim3(SEQ / 64, DIM / 64, NB), 256, 0, stream>>>(seq, xbT);

    // attended[b,s,:] = P[b,s,:] @ x[b]; write into out[s, b, :]
    dim3 gPV(DIM / 256, SEQ / 256, NB);
    gemm256<1><<<gPV, 512, 0, stream>>>(P, (size_t)SEQ * SEQ, xbT, (size_t)DIM * SEQ,
                                        out, (size_t)DIM, NB * DIM, SEQ, 1.0f);
}

// Round 5
// 388.207 us; speedup vs baseline: 1.4601x; 1.0242x over previous
//
#include <hip/hip_runtime.h>
#include <hip/hip_bf16.h>

#define SEQ 2048
#define NB 8
#define DIM 1024

typedef __attribute__((ext_vector_type(4))) float f32x4;
typedef __attribute__((ext_vector_type(8))) short bf16x8;
typedef __attribute__((ext_vector_type(4))) unsigned short u16x4;

__device__ __forceinline__ unsigned short f2bf(float f) {
    union { float f; unsigned u; } x; x.f = f;
    unsigned r = x.u + 0x7fffu + ((x.u >> 16) & 1u);
    return (unsigned short)(r >> 16);
}
__device__ __forceinline__ float bf2f(unsigned short u) {
    union { unsigned u; float f; } x; x.u = ((unsigned)u) << 16;
    return x.f;
}

// ------------- weight convert: 4x fp32 -> bf16 in one dispatch -------------
__global__ __launch_bounds__(256) void convert_w4(const float* __restrict__ s0,
                                                  const float* __restrict__ s1,
                                                  const float* __restrict__ s2,
                                                  const float* __restrict__ s3,
                                                  unsigned short* __restrict__ out) {
    int sel = blockIdx.y;
    const float* src = sel < 2 ? (sel == 0 ? s0 : s1) : (sel == 2 ? s2 : s3);
    int i = blockIdx.x * 256 + threadIdx.x;          // vec4 index within one W
    float4 v = reinterpret_cast<const float4*>(src)[i];
    u16x4 o = { f2bf(v.x), f2bf(v.y), f2bf(v.z), f2bf(v.w) };
    reinterpret_cast<u16x4*>(out + (size_t)sel * DIM * DIM)[i] = o;
}

// ---------------- xb[b][s][d] = bf16(seq[s][b][d]) ----------------
__global__ __launch_bounds__(256) void make_xb(const float* __restrict__ seq,
                                               unsigned short* __restrict__ xb) {
    int sb = blockIdx.x;
    int s = sb >> 3, b = sb & 7;
    const float4* src = reinterpret_cast<const float4*>(seq + (size_t)sb * DIM);
    u16x4* dst = reinterpret_cast<u16x4*>(xb + ((size_t)b * SEQ + s) * DIM);
    int t = threadIdx.x;
    float4 v = src[t];
    u16x4 o = { f2bf(v.x), f2bf(v.y), f2bf(v.z), f2bf(v.w) };
    dst[t] = o;
}

// ---------------- xbT[b][d][s] = bf16(seq[s][b][d]) ----------------
__global__ __launch_bounds__(256) void make_xbT(const float* __restrict__ seq,
                                                unsigned short* __restrict__ xbT) {
    __shared__ unsigned short tile[64][65];
    int s0 = blockIdx.x * 64, d0 = blockIdx.y * 64, b = blockIdx.z;
    int t = threadIdx.x;
    int dx = (t & 15) * 4, sy = t >> 4;
    #pragma unroll
    for (int i = 0; i < 4; ++i) {
        int s = s0 + sy + i * 16;
        float4 v = *reinterpret_cast<const float4*>(seq + ((size_t)s * NB + b) * DIM + d0 + dx);
        tile[sy + i * 16][dx + 0] = f2bf(v.x);
        tile[sy + i * 16][dx + 1] = f2bf(v.y);
        tile[sy + i * 16][dx + 2] = f2bf(v.z);
        tile[sy + i * 16][dx + 3] = f2bf(v.w);
    }
    __syncthreads();
    int sx = (t & 15) * 4, dy = t >> 4;
    #pragma unroll
    for (int i = 0; i < 4; ++i) {
        int d = d0 + dy + i * 16;
        u16x4 o = { tile[sx + 0][dy + i * 16], tile[sx + 1][dy + i * 16],
                    tile[sx + 2][dy + i * 16], tile[sx + 3][dy + i * 16] };
        *reinterpret_cast<u16x4*>(xbT + ((size_t)b * DIM + d) * SEQ + s0 + sx) = o;
    }
}

// =====================  256x256 8-phase GEMM  =====================
// Same verified schedule as round 4 (slot-freed distance-2 staging, vmcnt(8)),
// with: k-slice-outer MFMA order (dep distance 8), strength-reduced stage
// addressing (pointers advanced +64/iter, bufo ^= 16384), stages spread
// B0->P2, B1->P3, A0+A1->P4.
__device__ __forceinline__ void gload16(const unsigned short* g, unsigned short* l) {
    __builtin_amdgcn_global_load_lds((const __attribute__((address_space(1))) void*)g,
                                     (__attribute__((address_space(3))) void*)l,
                                     16, 0, 0);
}

#define QUAD(A0, A1)                                                                              \
    _Pragma("unroll")                                                                             \
    for (int ks = 0; ks < 2; ++ks)                                                                \
        _Pragma("unroll")                                                                         \
        for (int ni = 0; ni < 4; ++ni) {                                                          \
            acc[A0][ni] = __builtin_amdgcn_mfma_f32_16x16x32_bf16(a[A0][ks], b[ni][ks], acc[A0][ni], 0, 0, 0); \
            acc[A1][ni] = __builtin_amdgcn_mfma_f32_16x16x32_bf16(a[A1][ks], b[ni][ks], acc[A1][ni], 0, 0, 0); \
        }

// MODE 0: C bf16 = tanh(acc); MODE 1: C f32 = acc*scale (+sC*bz); MODE 2: C bf16 = acc*scale (+sC*bz)
template<int MODE>
__global__ __launch_bounds__(512, 2) void gemm256(
    const unsigned short* __restrict__ A, size_t sA,
    const unsigned short* __restrict__ B, size_t sB,
    void* __restrict__ Cv, size_t sC,
    int ldc, int K, float scale)
{
    __shared__ unsigned short AsF[2 * 2 * 8192];   // [buf][half][128*64]
    __shared__ unsigned short BsF[2 * 2 * 8192];

    // ---- T1: bijective XCD swizzle (all grids divisible by 8) ----
    const int gx = gridDim.x, gy = gridDim.y;
    const int nwg = gx * gy * gridDim.z;
    const int fid = blockIdx.x + gx * (blockIdx.y + gy * blockIdx.z);
    const int cpx = nwg >> 3;
    const int sw = (fid & 7) * cpx + (fid >> 3);
    const int bx = sw % gx;
    const int rem = sw / gx;
    const int by = rem % gy;
    const int bz = rem / gy;

    const unsigned short* Ab = A + sA * bz;
    const unsigned short* Bb = B + sB * bz;
    const int m0 = by * 256;
    const int n0 = bx * 256;

    const int t_ = threadIdx.x;
    const int lane = t_ & 63;
    const int w = t_ >> 6;
    const int wm = w >> 2;
    const int wn = w & 3;

    const int l3 = lane >> 3;
    const int g7 = lane & 7;
    const size_t h128 = (size_t)128 * K;    // half-tile row stride
    const size_t r8 = (size_t)8 * K;        // +8 rows
    // pre-swizzled source: LDS[row][g] holds global[row][g ^ (row&7)]
    const unsigned short* gA = Ab + (size_t)(m0 + w * 16 + l3) * K + ((g7 ^ l3) << 3);
    const unsigned short* gB = Bb + (size_t)(n0 + w * 16 + l3) * K + ((g7 ^ l3) << 3);

    // read-side fragment addressing
    const int fr = lane & 15;
    const int hi4 = lane >> 4;
    const int off0 = fr * 64 + (((hi4) ^ g7) << 3);
    const int off1 = fr * 64 + (((4 + hi4) ^ g7) << 3);
    const int bno = (wn & 1) * 4096;
    const int wlds = w * 1024;

    f32x4 acc[8][4] = {};
    const int NT = K >> 6;

    // ---- prologue: stage tiles 0 (buf0) and 1 (buf1); confirm tile0 ----
    #pragma unroll
    for (int kt = 0; kt < 2; ++kt) {
        unsigned short* lA = AsF + kt * 16384 + wlds;
        unsigned short* lB = BsF + kt * 16384 + wlds;
        const unsigned short* ga = gA + kt * 64;
        const unsigned short* gb = gB + kt * 64;
        gload16(ga, lA);                 gload16(ga + r8, lA + 512);
        gload16(ga + h128, lA + 8192);   gload16(ga + h128 + r8, lA + 8192 + 512);
        gload16(gb, lB);                 gload16(gb + r8, lB + 512);
        gload16(gb + h128, lB + 8192);   gload16(gb + h128 + r8, lB + 8192 + 512);
    }
    asm volatile("s_waitcnt vmcnt(8)" ::: "memory");
    __builtin_amdgcn_s_barrier();

    // steady-state stage pointers (kt = t+2)
    const unsigned short* gAs = gA + 128;
    const unsigned short* gBs = gB + 128;
    int bufo = 0;                           // read buf == stage buf (same parity)

    for (int t = 0; t < NT; ++t) {
        const unsigned short* pA = AsF + bufo + wm * 8192;
        const unsigned short* pB = BsF + bufo + (wn >> 1) * 8192 + bno;
        unsigned short* lA = AsF + bufo + wlds;
        unsigned short* lB = BsF + bufo + wlds;
        const bool pf = (t + 2 < NT);
        bf16x8 a[8][2], b[4][2];

        // ---------- P1: read b0-3 + a0,a1 ; MFMA a01 ----------
        #pragma unroll
        for (int j = 0; j < 4; ++j) {
            b[j][0] = *(const bf16x8*)&pB[j * 1024 + off0];
            b[j][1] = *(const bf16x8*)&pB[j * 1024 + off1];
        }
        #pragma unroll
        for (int i = 0; i < 2; ++i) {
            a[i][0] = *(const bf16x8*)&pA[i * 1024 + off0];
            a[i][1] = *(const bf16x8*)&pA[i * 1024 + off1];
        }
        __builtin_amdgcn_s_barrier();
        asm volatile("s_waitcnt lgkmcnt(0)" ::: "memory");
        __builtin_amdgcn_sched_barrier(0);
        __builtin_amdgcn_s_setprio(1);
        QUAD(0, 1)
        __builtin_amdgcn_s_setprio(0);
        __builtin_amdgcn_s_barrier();

        // ---------- P2: read a2,a3 ; stage B-half0(t+2) ; MFMA a23 ----------
        #pragma unroll
        for (int i = 2; i < 4; ++i) {
            a[i][0] = *(const bf16x8*)&pA[i * 1024 + off0];
            a[i][1] = *(const bf16x8*)&pA[i * 1024 + off1];
        }
        if (pf) { gload16(gBs, lB); gload16(gBs + r8, lB + 512); }
        __builtin_amdgcn_s_barrier();
        asm volatile("s_waitcnt lgkmcnt(0)" ::: "memory");
        __builtin_amdgcn_sched_barrier(0);
        __builtin_amdgcn_s_setprio(1);
        QUAD(2, 3)
        __builtin_amdgcn_s_setprio(0);
        __builtin_amdgcn_s_barrier();

        // ---------- P3: read a4-7 ; stage B-half1(t+2) ; MFMA a45 ----------
        #pragma unroll
        for (int i = 4; i < 8; ++i) {
            a[i][0] = *(const bf16x8*)&pA[i * 1024 + off0];
            a[i][1] = *(const bf16x8*)&pA[i * 1024 + off1];
        }
        if (pf) { gload16(gBs + h128, lB + 8192); gload16(gBs + h128 + r8, lB + 8192 + 512); }
        __builtin_amdgcn_s_barrier();
        asm volatile("s_waitcnt lgkmcnt(0)" ::: "memory");
        __builtin_amdgcn_sched_barrier(0);
        __builtin_amdgcn_s_setprio(1);
        QUAD(4, 5)
        __builtin_amdgcn_s_setprio(0);
        __builtin_amdgcn_s_barrier();

        // ---------- P4: stage A(t+2) both halves ; vmcnt ; MFMA a67 ----------
        if (pf) {
            gload16(gAs, lA);               gload16(gAs + r8, lA + 512);
            gload16(gAs + h128, lA + 8192); gload16(gAs + h128 + r8, lA + 8192 + 512);
            asm volatile("s_waitcnt vmcnt(8)" ::: "memory");  // confirms tile t+1
        } else {
            asm volatile("s_waitcnt vmcnt(0)" ::: "memory");
        }
        __builtin_amdgcn_s_barrier();
        __builtin_amdgcn_sched_barrier(0);
        __builtin_amdgcn_s_setprio(1);
        QUAD(6, 7)
        __builtin_amdgcn_s_setprio(0);
        __builtin_amdgcn_s_barrier();

        gAs += 64; gBs += 64; bufo ^= 16384;
    }

    // ---- epilogue: C/D layout col=lane&15, row=(lane>>4)*4+r ----
    #pragma unroll
    for (int mi = 0; mi < 8; ++mi)
        #pragma unroll
        for (int ni = 0; ni < 4; ++ni)
            #pragma unroll
            for (int r = 0; r < 4; ++r) {
                int row = m0 + wm * 128 + mi * 16 + hi4 * 4 + r;
                int col = n0 + wn * 64 + ni * 16 + fr;
                if (MODE == 0) {
                    unsigned short* C = reinterpret_cast<unsigned short*>(Cv);
                    C[(size_t)row * ldc + col] = f2bf(tanhf(acc[mi][ni][r]));
                } else if (MODE == 1) {
                    float* C = reinterpret_cast<float*>(Cv) + sC * bz;
                    C[(size_t)row * ldc + col] = acc[mi][ni][r] * scale;
                } else {
                    unsigned short* C = reinterpret_cast<unsigned short*>(Cv) + sC * bz;
                    C[(size_t)row * ldc + col] = f2bf(acc[mi][ni][r] * scale);
                }
            }
}

// ------------- in-place row softmax on bf16 logits ----------
__global__ __launch_bounds__(256) void softmax_rows_bf16(unsigned short* __restrict__ Z) {
    const size_t row = blockIdx.x;
    unsigned short* z = Z + row * SEQ;
    const int t = threadIdx.x;
    u16x4 v0 = reinterpret_cast<const u16x4*>(z)[2 * t];
    u16x4 v1 = reinterpret_cast<const u16x4*>(z)[2 * t + 1];
    float f[8] = { bf2f(v0[0]), bf2f(v0[1]), bf2f(v0[2]), bf2f(v0[3]),
                   bf2f(v1[0]), bf2f(v1[1]), bf2f(v1[2]), bf2f(v1[3]) };
    float m = f[0];
    #pragma unroll
    for (int j = 1; j < 8; ++j) m = fmaxf(m, f[j]);
    #pragma unroll
    for (int off = 32; off; off >>= 1) m = fmaxf(m, __shfl_xor(m, off, 64));
    __shared__ float redm[4], reds[4];
    const int w = t >> 6, lane = t & 63;
    if (lane == 0) redm[w] = m;
    __syncthreads();
    m = fmaxf(fmaxf(redm[0], redm[1]), fmaxf(redm[2], redm[3]));
    float e[8], s = 0.f;
    #pragma unroll
    for (int j = 0; j < 8; ++j) { e[j] = __expf(f[j] - m); s += e[j]; }
    #pragma unroll
    for (int off = 32; off; off >>= 1) s += __shfl_xor(s, off, 64);
    if (lane == 0) reds[w] = s;
    __syncthreads();
    s = reds[0] + reds[1] + reds[2] + reds[3];
    float inv = 1.0f / s;
    u16x4 o0 = { f2bf(e[0] * inv), f2bf(e[1] * inv), f2bf(e[2] * inv), f2bf(e[3] * inv) };
    u16x4 o1 = { f2bf(e[4] * inv), f2bf(e[5] * inv), f2bf(e[6] * inv), f2bf(e[7] * inv) };
    reinterpret_cast<u16x4*>(z)[2 * t] = o0;
    reinterpret_cast<u16x4*>(z)[2 * t + 1] = o1;
}

// ---------------- launch ----------------
extern "C" void kernel_launch(void* const* d_in, const int* in_sizes, int n_in,
                              void* d_out, int out_size, void* d_ws, size_t ws_size,
                              hipStream_t stream) {
    const float* seq  = (const float*)d_in[0];
    const float* Kw1f = (const float*)d_in[1];
    const float* Kw2f = (const float*)d_in[2];
    const float* Qw1f = (const float*)d_in[3];
    const float* Qw2f = (const float*)d_in[4];
    float* out = (float*)d_out;

    // Workspace (168 MiB): W 8 | xb/qrs 32 | h/xbT 32 | keys 32 | logits(P) 64
    char* ws = (char*)d_ws;
    size_t off = 0;
    auto alloc = [&](size_t bytes) { void* p = ws + off; off += bytes; return p; };
    const size_t WBYTES = (size_t)DIM * DIM * 2;
    const size_t XBYTES = (size_t)NB * SEQ * DIM * 2;
    unsigned short* Wk1 = (unsigned short*)alloc(4 * WBYTES);  // Wk1,Wk2,Wq1,Wq2 contiguous
    unsigned short* Wk2 = Wk1 + (size_t)DIM * DIM;
    unsigned short* Wq1 = Wk2 + (size_t)DIM * DIM;
    unsigned short* Wq2 = Wq1 + (size_t)DIM * DIM;
    unsigned short* xb   = (unsigned short*)alloc(XBYTES);   // reused as qrs
    unsigned short* hbuf = (unsigned short*)alloc(XBYTES);   // reused as xbT
    unsigned short* keys = (unsigned short*)alloc(XBYTES);
    unsigned short* P    = (unsigned short*)alloc((size_t)NB * SEQ * SEQ * 2);
    unsigned short* qrs = xb;
    unsigned short* xbT = hbuf;

    convert_w4<<<dim3(DIM * DIM / 4 / 256, 4), 256, 0, stream>>>(Kw1f, Kw2f, Qw1f, Qw2f, Wk1);
    make_xb<<<SEQ * NB, 256, 0, stream>>>(seq, xb);

    // MLPs: [16384,1024] x [1024,1024]^T, tanh epilogue
    dim3 gMLP(DIM / 256, (NB * SEQ) / 256, 1);
    gemm256<0><<<gMLP, 512, 0, stream>>>(xb,   0, Wk1, 0, hbuf, 0, DIM, DIM, 1.0f);
    gemm256<0><<<gMLP, 512, 0, stream>>>(hbuf, 0, Wk2, 0, keys, 0, DIM, DIM, 1.0f);
    gemm256<0><<<gMLP, 512, 0, stream>>>(xb,   0, Wq1, 0, hbuf, 0, DIM, DIM, 1.0f);
    gemm256<0><<<gMLP, 512, 0, stream>>>(hbuf, 0, Wq2, 0, qrs,  0, DIM, DIM, 1.0f);

    // logits[b,s,t] = keys[b,s,:].qrs[b,t,:] / sqrt(D)  (bf16 out)
    dim3 gQK(SEQ / 256, SEQ / 256, NB);
    gemm256<2><<<gQK, 512, 0, stream>>>(keys, (size_t)SEQ * DIM, qrs, (size_t)SEQ * DIM,
                                        P, (size_t)SEQ * SEQ, SEQ, DIM, 0.03125f);

    softmax_rows_bf16<<<NB * SEQ, 256, 0, stream>>>(P);

    make_xbT<<<dim3(SEQ / 64, DIM / 64, NB), 256, 0, stream>>>(seq, xbT);

    // attended[b,s,:] = P[b,s,:] @ x[b]; write into out[s, b, :]
    dim3 gPV(DIM / 256, SEQ / 256, NB);
    gemm256<1><<<gPV, 512, 0, stream>>>(P, (size_t)SEQ * SEQ, xbT, (size_t)DIM * SEQ,
                                        out, (size_t)DIM, NB * DIM, SEQ, 1.0f);
}

// Round 6
// 386.443 us; speedup vs baseline: 1.4668x; 1.0046x over previous
//
#include <hip/hip_runtime.h>
#include <hip/hip_bf16.h>

#define SEQ 2048
#define NB 8
#define DIM 1024

typedef __attribute__((ext_vector_type(4))) float f32x4;
typedef __attribute__((ext_vector_type(8))) short bf16x8;
typedef __attribute__((ext_vector_type(4))) unsigned short u16x4;

__device__ __forceinline__ unsigned short f2bf(float f) {
    union { float f; unsigned u; } x; x.f = f;
    unsigned r = x.u + 0x7fffu + ((x.u >> 16) & 1u);
    return (unsigned short)(r >> 16);
}
__device__ __forceinline__ float bf2f(unsigned short u) {
    union { unsigned u; float f; } x; x.u = ((unsigned)u) << 16;
    return x.f;
}

// ------------- weight convert: 4x fp32 -> bf16 in one dispatch -------------
__global__ __launch_bounds__(256) void convert_w4(const float* __restrict__ s0,
                                                  const float* __restrict__ s1,
                                                  const float* __restrict__ s2,
                                                  const float* __restrict__ s3,
                                                  unsigned short* __restrict__ out) {
    int sel = blockIdx.y;
    const float* src = sel < 2 ? (sel == 0 ? s0 : s1) : (sel == 2 ? s2 : s3);
    int i = blockIdx.x * 256 + threadIdx.x;
    float4 v = reinterpret_cast<const float4*>(src)[i];
    u16x4 o = { f2bf(v.x), f2bf(v.y), f2bf(v.z), f2bf(v.w) };
    reinterpret_cast<u16x4*>(out + (size_t)sel * DIM * DIM)[i] = o;
}

// ---------------- xb[b][s][d] = bf16(seq[s][b][d]) ----------------
__global__ __launch_bounds__(256) void make_xb(const float* __restrict__ seq,
                                               unsigned short* __restrict__ xb) {
    int sb = blockIdx.x;
    int s = sb >> 3, b = sb & 7;
    const float4* src = reinterpret_cast<const float4*>(seq + (size_t)sb * DIM);
    u16x4* dst = reinterpret_cast<u16x4*>(xb + ((size_t)b * SEQ + s) * DIM);
    int t = threadIdx.x;
    float4 v = src[t];
    u16x4 o = { f2bf(v.x), f2bf(v.y), f2bf(v.z), f2bf(v.w) };
    dst[t] = o;
}

// ---------------- xbT[b][d][s] = bf16(seq[s][b][d]) ----------------
__global__ __launch_bounds__(256) void make_xbT(const float* __restrict__ seq,
                                                unsigned short* __restrict__ xbT) {
    __shared__ unsigned short tile[64][65];
    int s0 = blockIdx.x * 64, d0 = blockIdx.y * 64, b = blockIdx.z;
    int t = threadIdx.x;
    int dx = (t & 15) * 4, sy = t >> 4;
    #pragma unroll
    for (int i = 0; i < 4; ++i) {
        int s = s0 + sy + i * 16;
        float4 v = *reinterpret_cast<const float4*>(seq + ((size_t)s * NB + b) * DIM + d0 + dx);
        tile[sy + i * 16][dx + 0] = f2bf(v.x);
        tile[sy + i * 16][dx + 1] = f2bf(v.y);
        tile[sy + i * 16][dx + 2] = f2bf(v.z);
        tile[sy + i * 16][dx + 3] = f2bf(v.w);
    }
    __syncthreads();
    int sx = (t & 15) * 4, dy = t >> 4;
    #pragma unroll
    for (int i = 0; i < 4; ++i) {
        int d = d0 + dy + i * 16;
        u16x4 o = { tile[sx + 0][dy + i * 16], tile[sx + 1][dy + i * 16],
                    tile[sx + 2][dy + i * 16], tile[sx + 3][dy + i * 16] };
        *reinterpret_cast<u16x4*>(xbT + ((size_t)b * DIM + d) * SEQ + s0 + sx) = o;
    }
}

// =====================  256x256 8-phase GEMM (m201-faithful ring)  ============
// Per K-tile u (4 phases), 1 half-tile staged per phase, ring order:
//   Ph0: read a0-3,b01 (12) ; stage A0(u+1) ; lgkm(8) ; MFMA q00
//   Ph1: read b23      (4)  ; stage A1(u+1) ;           MFMA q01
//   Ph2: read a4-7     (8)  ; stage B0(u+2) ;           MFMA q10
//   Ph3:                      stage B1(u+2) ; vmcnt(4) ; MFMA q11
// vmcnt(4) leaves B(u+2)'s 4 loads in flight, confirms A(u+1) (+older).
// Slot-freed safety: A(u+1)->other buf (last read tile u-1 Ph2); B(u+2)->
// current buf (B reads complete after Ph1's lgkm+barrier).
__device__ __forceinline__ void gload16(const unsigned short* g, unsigned short* l) {
    __builtin_amdgcn_global_load_lds((const __attribute__((address_space(1))) void*)g,
                                     (__attribute__((address_space(3))) void*)l,
                                     16, 0, 0);
}

#define MFMA16(I0, J0)                                                                            \
    _Pragma("unroll")                                                                             \
    for (int ks = 0; ks < 2; ++ks)                                                                \
        _Pragma("unroll")                                                                         \
        for (int ii = 0; ii < 4; ++ii)                                                            \
            _Pragma("unroll")                                                                     \
            for (int jj = 0; jj < 2; ++jj)                                                        \
                acc[I0 + ii][J0 + jj] = __builtin_amdgcn_mfma_f32_16x16x32_bf16(                   \
                    a[I0 + ii][ks], b[J0 + jj][ks], acc[I0 + ii][J0 + jj], 0, 0, 0);

// MODE 0: C bf16 = tanh(acc); MODE 1: C f32 = acc*scale (+sC*bz); MODE 2: C bf16 = acc*scale (+sC*bz)
template<int MODE>
__global__ __launch_bounds__(512, 2) void gemm256(
    const unsigned short* __restrict__ A, size_t sA,
    const unsigned short* __restrict__ B, size_t sB,
    void* __restrict__ Cv, size_t sC,
    int ldc, int K, float scale)
{
    __shared__ unsigned short AsF[2 * 2 * 8192];   // [buf][half][128*64]
    __shared__ unsigned short BsF[2 * 2 * 8192];

    // ---- T1: bijective XCD swizzle (all grids divisible by 8) ----
    const int gx = gridDim.x, gy = gridDim.y;
    const int nwg = gx * gy * gridDim.z;
    const int fid = blockIdx.x + gx * (blockIdx.y + gy * blockIdx.z);
    const int cpx = nwg >> 3;
    const int sw = (fid & 7) * cpx + (fid >> 3);
    const int bx = sw % gx;
    const int rem = sw / gx;
    const int by = rem % gy;
    const int bz = rem / gy;

    const unsigned short* Ab = A + sA * bz;
    const unsigned short* Bb = B + sB * bz;
    const int m0 = by * 256;
    const int n0 = bx * 256;

    const int t_ = threadIdx.x;
    const int lane = t_ & 63;
    const int w = t_ >> 6;
    const int wm = w >> 2;
    const int wn = w & 3;

    const int l3 = lane >> 3;
    const int g7 = lane & 7;
    const size_t h128 = (size_t)128 * K;
    const size_t r8 = (size_t)8 * K;
    // pre-swizzled source: LDS[row][g] holds global[row][g ^ (row&7)]
    const unsigned short* gA = Ab + (size_t)(m0 + w * 16 + l3) * K + ((g7 ^ l3) << 3);
    const unsigned short* gB = Bb + (size_t)(n0 + w * 16 + l3) * K + ((g7 ^ l3) << 3);

    // read-side fragment addressing
    const int fr = lane & 15;
    const int hi4 = lane >> 4;
    const int off0 = fr * 64 + (((hi4) ^ g7) << 3);
    const int off1 = fr * 64 + (((4 + hi4) ^ g7) << 3);
    const int bno = (wn & 1) * 4096;
    const int wlds = w * 1024;

    f32x4 acc[8][4] = {};
    const int NT = K >> 6;

    // ---- prologue: tile0 {A0,A1,B0,B1} -> buf0; tile1 {B0,B1} -> buf1 ----
    gload16(gA, AsF + wlds);                    gload16(gA + r8, AsF + wlds + 512);
    gload16(gA + h128, AsF + 8192 + wlds);      gload16(gA + h128 + r8, AsF + 8192 + wlds + 512);
    gload16(gB, BsF + wlds);                    gload16(gB + r8, BsF + wlds + 512);
    gload16(gB + h128, BsF + 8192 + wlds);      gload16(gB + h128 + r8, BsF + 8192 + wlds + 512);
    {
        const unsigned short* gb1 = gB + 64;
        gload16(gb1, BsF + 16384 + wlds);               gload16(gb1 + r8, BsF + 16384 + wlds + 512);
        gload16(gb1 + h128, BsF + 16384 + 8192 + wlds); gload16(gb1 + h128 + r8, BsF + 16384 + 8192 + wlds + 512);
    }
    asm volatile("s_waitcnt vmcnt(4)" ::: "memory");   // tile0 landed; B(1) in flight
    __builtin_amdgcn_s_barrier();

    const unsigned short* gA1 = gA + 64;     // A(u+1) source
    const unsigned short* gB2 = gB + 128;    // B(u+2) source

    for (int u = 0; u < NT; ++u) {
        const int bu = (u & 1) * 16384;          // current buf
        const int bn = 16384 - bu;               // next buf
        const unsigned short* pA = AsF + bu + wm * 8192;
        const unsigned short* pB = BsF + bu + (wn >> 1) * 8192 + bno;
        const bool pfA = (u + 1 < NT);
        const bool pfB = (u + 2 < NT);
        bf16x8 a[8][2], b[4][2];

        // ---------- Ph0: read a0-3 + b01 ; stage A0(u+1) ; MFMA q00 ----------
        #pragma unroll
        for (int i = 0; i < 4; ++i) {
            a[i][0] = *(const bf16x8*)&pA[i * 1024 + off0];
            a[i][1] = *(const bf16x8*)&pA[i * 1024 + off1];
        }
        #pragma unroll
        for (int j = 0; j < 2; ++j) {
            b[j][0] = *(const bf16x8*)&pB[j * 1024 + off0];
            b[j][1] = *(const bf16x8*)&pB[j * 1024 + off1];
        }
        if (pfA) { gload16(gA1, AsF + bn + wlds); gload16(gA1 + r8, AsF + bn + wlds + 512); }
        asm volatile("s_waitcnt lgkmcnt(8)" ::: "memory");
        __builtin_amdgcn_s_barrier();
        asm volatile("s_waitcnt lgkmcnt(0)" ::: "memory");
        __builtin_amdgcn_sched_barrier(0);
        __builtin_amdgcn_s_setprio(1);
        MFMA16(0, 0)
        __builtin_amdgcn_s_setprio(0);
        __builtin_amdgcn_s_barrier();

        // ---------- Ph1: read b23 ; stage A1(u+1) ; MFMA q01 ----------
        #pragma unroll
        for (int j = 2; j < 4; ++j) {
            b[j][0] = *(const bf16x8*)&pB[j * 1024 + off0];
            b[j][1] = *(const bf16x8*)&pB[j * 1024 + off1];
        }
        if (pfA) { gload16(gA1 + h128, AsF + bn + 8192 + wlds); gload16(gA1 + h128 + r8, AsF + bn + 8192 + wlds + 512); }
        __builtin_amdgcn_s_barrier();
        asm volatile("s_waitcnt lgkmcnt(0)" ::: "memory");
        __builtin_amdgcn_sched_barrier(0);
        __builtin_amdgcn_s_setprio(1);
        MFMA16(0, 2)
        __builtin_amdgcn_s_setprio(0);
        __builtin_amdgcn_s_barrier();

        // ---------- Ph2: read a4-7 ; stage B0(u+2) ; MFMA q10 ----------
        #pragma unroll
        for (int i = 4; i < 8; ++i) {
            a[i][0] = *(const bf16x8*)&pA[i * 1024 + off0];
            a[i][1] = *(const bf16x8*)&pA[i * 1024 + off1];
        }
        if (pfB) { gload16(gB2, BsF + bu + wlds); gload16(gB2 + r8, BsF + bu + wlds + 512); }
        __builtin_amdgcn_s_barrier();
        asm volatile("s_waitcnt lgkmcnt(0)" ::: "memory");
        __builtin_amdgcn_sched_barrier(0);
        __builtin_amdgcn_s_setprio(1);
        MFMA16(4, 0)
        __builtin_amdgcn_s_setprio(0);
        __builtin_amdgcn_s_barrier();

        // ---------- Ph3: stage B1(u+2) ; vmcnt ; MFMA q11 ----------
        if (pfB) {
            gload16(gB2 + h128, BsF + bu + 8192 + wlds);
            gload16(gB2 + h128 + r8, BsF + bu + 8192 + wlds + 512);
            asm volatile("s_waitcnt vmcnt(4)" ::: "memory");   // confirms A(u+1)+older
        } else {
            asm volatile("s_waitcnt vmcnt(0)" ::: "memory");
        }
        __builtin_amdgcn_s_barrier();
        __builtin_amdgcn_sched_barrier(0);
        __builtin_amdgcn_s_setprio(1);
        MFMA16(4, 2)
        __builtin_amdgcn_s_setprio(0);
        __builtin_amdgcn_s_barrier();

        gA1 += 64; gB2 += 64;
    }

    // ---- epilogue: C/D layout col=lane&15, row=(lane>>4)*4+r ----
    #pragma unroll
    for (int mi = 0; mi < 8; ++mi)
        #pragma unroll
        for (int ni = 0; ni < 4; ++ni)
            #pragma unroll
            for (int r = 0; r < 4; ++r) {
                int row = m0 + wm * 128 + mi * 16 + hi4 * 4 + r;
                int col = n0 + wn * 64 + ni * 16 + fr;
                if (MODE == 0) {
                    unsigned short* C = reinterpret_cast<unsigned short*>(Cv);
                    C[(size_t)row * ldc + col] = f2bf(tanhf(acc[mi][ni][r]));
                } else if (MODE == 1) {
                    float* C = reinterpret_cast<float*>(Cv) + sC * bz;
                    C[(size_t)row * ldc + col] = acc[mi][ni][r] * scale;
                } else {
                    unsigned short* C = reinterpret_cast<unsigned short*>(Cv) + sC * bz;
                    C[(size_t)row * ldc + col] = f2bf(acc[mi][ni][r] * scale);
                }
            }
}

// ------------- in-place row softmax on bf16 logits ----------
__global__ __launch_bounds__(256) void softmax_rows_bf16(unsigned short* __restrict__ Z) {
    const size_t row = blockIdx.x;
    unsigned short* z = Z + row * SEQ;
    const int t = threadIdx.x;
    u16x4 v0 = reinterpret_cast<const u16x4*>(z)[2 * t];
    u16x4 v1 = reinterpret_cast<const u16x4*>(z)[2 * t + 1];
    float f[8] = { bf2f(v0[0]), bf2f(v0[1]), bf2f(v0[2]), bf2f(v0[3]),
                   bf2f(v1[0]), bf2f(v1[1]), bf2f(v1[2]), bf2f(v1[3]) };
    float m = f[0];
    #pragma unroll
    for (int j = 1; j < 8; ++j) m = fmaxf(m, f[j]);
    #pragma unroll
    for (int off = 32; off; off >>= 1) m = fmaxf(m, __shfl_xor(m, off, 64));
    __shared__ float redm[4], reds[4];
    const int w = t >> 6, lane = t & 63;
    if (lane == 0) redm[w] = m;
    __syncthreads();
    m = fmaxf(fmaxf(redm[0], redm[1]), fmaxf(redm[2], redm[3]));
    float e[8], s = 0.f;
    #pragma unroll
    for (int j = 0; j < 8; ++j) { e[j] = __expf(f[j] - m); s += e[j]; }
    #pragma unroll
    for (int off = 32; off; off >>= 1) s += __shfl_xor(s, off, 64);
    if (lane == 0) reds[w] = s;
    __syncthreads();
    s = reds[0] + reds[1] + reds[2] + reds[3];
    float inv = 1.0f / s;
    u16x4 o0 = { f2bf(e[0] * inv), f2bf(e[1] * inv), f2bf(e[2] * inv), f2bf(e[3] * inv) };
    u16x4 o1 = { f2bf(e[4] * inv), f2bf(e[5] * inv), f2bf(e[6] * inv), f2bf(e[7] * inv) };
    reinterpret_cast<u16x4*>(z)[2 * t] = o0;
    reinterpret_cast<u16x4*>(z)[2 * t + 1] = o1;
}

// ---------------- launch ----------------
extern "C" void kernel_launch(void* const* d_in, const int* in_sizes, int n_in,
                              void* d_out, int out_size, void* d_ws, size_t ws_size,
                              hipStream_t stream) {
    const float* seq  = (const float*)d_in[0];
    const float* Kw1f = (const float*)d_in[1];
    const float* Kw2f = (const float*)d_in[2];
    const float* Qw1f = (const float*)d_in[3];
    const float* Qw2f = (const float*)d_in[4];
    float* out = (float*)d_out;

    // Workspace (168 MiB): W 8 | xb/qrs 32 | h/xbT 32 | keys 32 | logits(P) 64
    char* ws = (char*)d_ws;
    size_t off = 0;
    auto alloc = [&](size_t bytes) { void* p = ws + off; off += bytes; return p; };
    const size_t WBYTES = (size_t)DIM * DIM * 2;
    const size_t XBYTES = (size_t)NB * SEQ * DIM * 2;
    unsigned short* Wk1 = (unsigned short*)alloc(4 * WBYTES);
    unsigned short* Wk2 = Wk1 + (size_t)DIM * DIM;
    unsigned short* Wq1 = Wk2 + (size_t)DIM * DIM;
    unsigned short* Wq2 = Wq1 + (size_t)DIM * DIM;
    unsigned short* xb   = (unsigned short*)alloc(XBYTES);   // reused as qrs
    unsigned short* hbuf = (unsigned short*)alloc(XBYTES);   // reused as xbT
    unsigned short* keys = (unsigned short*)alloc(XBYTES);
    unsigned short* P    = (unsigned short*)alloc((size_t)NB * SEQ * SEQ * 2);
    unsigned short* qrs = xb;
    unsigned short* xbT = hbuf;

    convert_w4<<<dim3(DIM * DIM / 4 / 256, 4), 256, 0, stream>>>(Kw1f, Kw2f, Qw1f, Qw2f, Wk1);
    make_xb<<<SEQ * NB, 256, 0, stream>>>(seq, xb);

    // MLPs: [16384,1024] x [1024,1024]^T, tanh epilogue
    dim3 gMLP(DIM / 256, (NB * SEQ) / 256, 1);
    gemm256<0><<<gMLP, 512, 0, stream>>>(xb,   0, Wk1, 0, hbuf, 0, DIM, DIM, 1.0f);
    gemm256<0><<<gMLP, 512, 0, stream>>>(hbuf, 0, Wk2, 0, keys, 0, DIM, DIM, 1.0f);
    gemm256<0><<<gMLP, 512, 0, stream>>>(xb,   0, Wq1, 0, hbuf, 0, DIM, DIM, 1.0f);
    gemm256<0><<<gMLP, 512, 0, stream>>>(hbuf, 0, Wq2, 0, qrs,  0, DIM, DIM, 1.0f);

    // logits[b,s,t] = keys[b,s,:].qrs[b,t,:] / sqrt(D)  (bf16 out)
    dim3 gQK(SEQ / 256, SEQ / 256, NB);
    gemm256<2><<<gQK, 512, 0, stream>>>(keys, (size_t)SEQ * DIM, qrs, (size_t)SEQ * DIM,
                                        P, (size_t)SEQ * SEQ, SEQ, DIM, 0.03125f);

    softmax_rows_bf16<<<NB * SEQ, 256, 0, stream>>>(P);

    make_xbT<<<dim3(SEQ / 64, DIM / 64, NB), 256, 0, stream>>>(seq, xbT);

    // attended[b,s,:] = P[b,s,:] @ x[b]; write into out[s, b, :]
    dim3 gPV(DIM / 256, SEQ / 256, NB);
    gemm256<1><<<gPV, 512, 0, stream>>>(P, (size_t)SEQ * SEQ, xbT, (size_t)DIM * SEQ,
                                        out, (size_t)DIM, NB * DIM, SEQ, 1.0f);
}